// Round 10
// baseline (413.121 us; speedup 1.0000x reference)
//
#include <hip/hip_runtime.h>
#include <cstddef>

#define NN   16000          // nodes
#define NE   256000         // edges (without self loops)
#define EP   (NE + NN)      // 272000 with self loops
#define BG   32             // graphs
#define IN_F 768
#define HID  256
#define H1C  4
#define F1   (H1C * HID)    // 1024
#define OUTF 128
#define H2C  2
#define F2   (H2C * OUTF)   // 256

typedef __bf16 bf16x8 __attribute__((ext_vector_type(8)));
typedef float  f32x4  __attribute__((ext_vector_type(4)));
typedef float  f32x2  __attribute__((ext_vector_type(2)));
typedef unsigned short us8 __attribute__((ext_vector_type(8)));
typedef unsigned short us4 __attribute__((ext_vector_type(4)));

static __device__ __forceinline__ float lrelu02(float x) { return x > 0.f ? x : 0.2f * x; }
static __device__ __forceinline__ float eluf(float x)    { return x > 0.f ? x : expm1f(x); }
static __device__ __forceinline__ unsigned short rne_bf16(float f) {
    unsigned u = __float_as_uint(f);
    return (unsigned short)((u + 0x7fffu + ((u >> 16) & 1u)) >> 16);
}
static __device__ __forceinline__ f32x2 cvt2(unsigned int u) {
    f32x2 r;
    r.x = __uint_as_float(u << 16);
    r.y = __uint_as_float(u & 0xffff0000u);
    return r;
}

#define GLDS16(gp, lp) __builtin_amdgcn_global_load_lds(                         \
    (const __attribute__((address_space(1))) void*)(gp),                          \
    (__attribute__((address_space(3))) void*)(lp), 16, 0, 0)

// ---------------- prep mega-kernel: 3x f2b + hist ----------------
#define NB_X  ((NN * IN_F) / 1024)      // 12000
#define NB_W1 ((F1 * IN_F) / 1024)      // 768
#define NB_W2 ((F2 * F1) / 1024)        // 256
#define NB_H  ((EP + 255) / 256)        // 1063
#define NB_PREP (NB_X + NB_W1 + NB_W2 + NB_H)

static __device__ __forceinline__ void f2b_body(const float* __restrict__ in,
                                                unsigned short* __restrict__ out,
                                                int blk, int t) {
    int i = (blk * 256 + t) * 4;
    float4 v = *(const float4*)&in[i];
    ushort4 o;
    o.x = rne_bf16(v.x); o.y = rne_bf16(v.y); o.z = rne_bf16(v.z); o.w = rne_bf16(v.w);
    *(ushort4*)&out[i] = o;
}

__global__ __launch_bounds__(256) void k_prep(const float* __restrict__ x,
                                              const float* __restrict__ W1,
                                              const float* __restrict__ W2,
                                              unsigned short* __restrict__ xb,
                                              unsigned short* __restrict__ W1b,
                                              unsigned short* __restrict__ W2b,
                                              const int* __restrict__ ei,
                                              int* __restrict__ deg) {
    int b = blockIdx.x, t = threadIdx.x;
    if (b < NB_X) { f2b_body(x, xb, b, t); return; }
    b -= NB_X;
    if (b < NB_W1) { f2b_body(W1, W1b, b, t); return; }
    b -= NB_W1;
    if (b < NB_W2) { f2b_body(W2, W2b, b, t); return; }
    b -= NB_W2;
    int e = b * 256 + t;
    if (e >= EP) return;
    int d = (e < NE) ? ei[NE + e] : (e - NE);
    atomicAdd(&deg[d], 1);
}

__global__ __launch_bounds__(1024) void k_scan(const int* __restrict__ deg,
                                               int* __restrict__ off, int* __restrict__ cursor) {
    __shared__ int sums[1024];
    int t = threadIdx.x;
    const int CH = 16;
    int base = t * CH;
    int s = 0;
    for (int i = 0; i < CH; ++i) { int idx = base + i; if (idx < NN) s += deg[idx]; }
    sums[t] = s;
    __syncthreads();
    for (int ofs = 1; ofs < 1024; ofs <<= 1) {
        int v = 0;
        if (t >= ofs) v = sums[t - ofs];
        __syncthreads();
        sums[t] += v;
        __syncthreads();
    }
    int run = sums[t] - s;
    for (int i = 0; i < CH; ++i) {
        int idx = base + i;
        if (idx < NN) { off[idx] = run; cursor[idx] = run; run += deg[idx]; }
    }
    if (t == 1023) off[NN] = run;
}

// ------- BM=128 BN=128 BK=32 bf16 MFMA GEMM body, 2-phase dbuf + swizzled LDS -----
// r10: (a) T3 minimum 2-phase pipeline: stage tile it+1 into the other 16KB half
// while computing tile it (GLDS latency hides under ds_read+MFMA); (b) bank-
// conflict fix per rule #21: source pre-swizzle qsw=(t&3)^((t>>3)&3) + read-slot
// slot=(lane>>4)^((lane>>1)&3), LDS dest stays GLDS-linear. Audit: per-wave b128
// read now touches every bank exactly 8 dwords (was 32 on banks 0-3; 3.07M
// conflicts measured r9). Slot is invariant across the 4 row-frags (+16 rows
// preserves (row>>1)&3). C/D + alpha epilogue mapping unchanged (verified r0-r9).
#define GEMM_MM16(POFS)                                                              \
    {   bf16x8 a0 = pa[(POFS)], a1 = pa[(POFS) + 64], a2 = pa[(POFS) + 128],         \
               a3 = pa[(POFS) + 192];                                                \
        bf16x8 b0 = pb[(POFS)], b1 = pb[(POFS) + 64], b2 = pb[(POFS) + 128],         \
               b3 = pb[(POFS) + 192];                                                \
        acc[0][0] = __builtin_amdgcn_mfma_f32_16x16x32_bf16(a0, b0, acc[0][0], 0, 0, 0); \
        acc[0][1] = __builtin_amdgcn_mfma_f32_16x16x32_bf16(a0, b1, acc[0][1], 0, 0, 0); \
        acc[0][2] = __builtin_amdgcn_mfma_f32_16x16x32_bf16(a0, b2, acc[0][2], 0, 0, 0); \
        acc[0][3] = __builtin_amdgcn_mfma_f32_16x16x32_bf16(a0, b3, acc[0][3], 0, 0, 0); \
        acc[1][0] = __builtin_amdgcn_mfma_f32_16x16x32_bf16(a1, b0, acc[1][0], 0, 0, 0); \
        acc[1][1] = __builtin_amdgcn_mfma_f32_16x16x32_bf16(a1, b1, acc[1][1], 0, 0, 0); \
        acc[1][2] = __builtin_amdgcn_mfma_f32_16x16x32_bf16(a1, b2, acc[1][2], 0, 0, 0); \
        acc[1][3] = __builtin_amdgcn_mfma_f32_16x16x32_bf16(a1, b3, acc[1][3], 0, 0, 0); \
        acc[2][0] = __builtin_amdgcn_mfma_f32_16x16x32_bf16(a2, b0, acc[2][0], 0, 0, 0); \
        acc[2][1] = __builtin_amdgcn_mfma_f32_16x16x32_bf16(a2, b1, acc[2][1], 0, 0, 0); \
        acc[2][2] = __builtin_amdgcn_mfma_f32_16x16x32_bf16(a2, b2, acc[2][2], 0, 0, 0); \
        acc[2][3] = __builtin_amdgcn_mfma_f32_16x16x32_bf16(a2, b3, acc[2][3], 0, 0, 0); \
        acc[3][0] = __builtin_amdgcn_mfma_f32_16x16x32_bf16(a3, b0, acc[3][0], 0, 0, 0); \
        acc[3][1] = __builtin_amdgcn_mfma_f32_16x16x32_bf16(a3, b1, acc[3][1], 0, 0, 0); \
        acc[3][2] = __builtin_amdgcn_mfma_f32_16x16x32_bf16(a3, b2, acc[3][2], 0, 0, 0); \
        acc[3][3] = __builtin_amdgcn_mfma_f32_16x16x32_bf16(a3, b3, acc[3][3], 0, 0, 0); }

#define GEMM_STAGE(IT, OFS)                                                          \
    {   const unsigned short* pA_ = ga0 + (IT) * 32;                                 \
        const unsigned short* pB_ = gb0 + (IT) * 32;                                 \
        GLDS16(pA_, lA0 + (OFS)); GLDS16(pA_ + K64, lA1 + (OFS));                    \
        GLDS16(pB_, lB0 + (OFS)); GLDS16(pB_ + K64, lB1 + (OFS)); }

template <int KITER, int HSHIFT, int HCNT>
static __device__ __forceinline__ void gemm_body(const unsigned short* __restrict__ A,
                                                 const unsigned short* __restrict__ B,
                                                 unsigned short* __restrict__ C,
                                                 const float* __restrict__ a_s,
                                                 const float* __restrict__ a_d,
                                                 float* __restrict__ as_o,
                                                 float* __restrict__ ad_o,
                                                 int N, int K, int bx, int by,
                                                 unsigned short* As, unsigned short* Bs,
                                                 int t) {
    const int w = t >> 6, lane = t & 63;
    const int m0 = by * 128, n0 = bx * 128;
    const int wm = (w >> 1) * 64, wn = (w & 1) * 64;

    const int qsw = (t & 3) ^ ((t >> 3) & 3);        // pre-swizzled source quarter
    const unsigned short* ga0 = A + (size_t)(m0 + (t >> 2)) * K + qsw * 8;
    const unsigned short* gb0 = B + (size_t)(n0 + (t >> 2)) * K + qsw * 8;
    const size_t K64 = (size_t)64 * K;

    unsigned short* lA0 = &As[w * 512];              // buf0, rows 0..63 (wave quarter)
    unsigned short* lA1 = &As[w * 512 + 2048];       // buf0, rows 64..127
    unsigned short* lB0 = &Bs[w * 512];
    unsigned short* lB1 = &Bs[w * 512 + 2048];

    f32x4 acc[4][4] = {};

    const int slot = (lane >> 4) ^ ((lane >> 1) & 3);   // swizzled read slot
    const bf16x8* pa = (const bf16x8*)As + (wm + (lane & 15)) * 4 + slot;
    const bf16x8* pb = (const bf16x8*)Bs + (wn + (lane & 15)) * 4 + slot;

    GEMM_STAGE(0, 0);
    asm volatile("s_waitcnt vmcnt(0)" ::: "memory");
    __syncthreads();
    for (int it = 0; it < KITER; it += 2) {
        GEMM_STAGE(it + 1, 4096);                    // stage buf1 while computing buf0
        GEMM_MM16(0);
        asm volatile("s_waitcnt vmcnt(0)" ::: "memory");
        __syncthreads();
        if (it + 2 < KITER) GEMM_STAGE(it + 2, 0);   // stage buf0 while computing buf1
        GEMM_MM16(512);
        asm volatile("s_waitcnt vmcnt(0)" ::: "memory");
        __syncthreads();
    }
    const int ccol = n0 + wn + (lane & 15);
    const int crow = m0 + wm + (lane >> 4) * 4;
#pragma unroll
    for (int mi = 0; mi < 4; ++mi)
#pragma unroll
        for (int i = 0; i < 4; ++i) {
            unsigned short* cp = C + (size_t)(crow + mi * 16 + i) * N + ccol;
            cp[0]  = rne_bf16(acc[mi][0][i]);
            cp[16] = rne_bf16(acc[mi][1][i]);
            cp[32] = rne_bf16(acc[mi][2][i]);
            cp[48] = rne_bf16(acc[mi][3][i]);
        }
    const int hh = n0 >> HSHIFT;
    float asv[4], adv[4];
#pragma unroll
    for (int bi = 0; bi < 4; ++bi) {
        asv[bi] = a_s[ccol + bi * 16];
        adv[bi] = a_d[ccol + bi * 16];
    }
#pragma unroll
    for (int mi = 0; mi < 4; ++mi)
#pragma unroll
        for (int i = 0; i < 4; ++i) {
            float vs = acc[mi][0][i] * asv[0] + acc[mi][1][i] * asv[1]
                     + acc[mi][2][i] * asv[2] + acc[mi][3][i] * asv[3];
            float vd = acc[mi][0][i] * adv[0] + acc[mi][1][i] * adv[1]
                     + acc[mi][2][i] * adv[2] + acc[mi][3][i] * adv[3];
#pragma unroll
            for (int m = 1; m <= 8; m <<= 1) {
                vs += __shfl_xor(vs, m);
                vd += __shfl_xor(vd, m);
            }
            if ((lane & 15) == 0) {
                int r = crow + mi * 16 + i;
                atomicAdd(&as_o[r * HCNT + hh], vs);
                atomicAdd(&ad_o[r * HCNT + hh], vd);
            }
        }
}

// GEMM1: 125 panels x 8 col-blocks (BM=128); panel -> one XCD (weights L2-fit);
// CSR scatter as sequential tail blocks.
#define G1_BLKS 1024
__global__ __launch_bounds__(256) void k_gemm1(const unsigned short* __restrict__ A,
                                               const unsigned short* __restrict__ B,
                                               unsigned short* __restrict__ C,
                                               const float* __restrict__ a_s,
                                               const float* __restrict__ a_d,
                                               float* __restrict__ as_o,
                                               float* __restrict__ ad_o,
                                               const int* __restrict__ ei,
                                               int* __restrict__ cursor,
                                               int* __restrict__ csr_src,
                                               int* __restrict__ csr_dst) {
    __shared__ __align__(16) unsigned short As[8192];   // 2 x 16KB halves (A,B each 8KB/half)
    __shared__ __align__(16) unsigned short Bs[8192];
    int blk = blockIdx.x, t = threadIdx.x;
    if (blk < G1_BLKS) {
        int by = (blk & 7) + 8 * (blk >> 6);
        int bx = (blk >> 3) & 7;
        if (by < 125)
            gemm_body<24, 8, 4>(A, B, C, a_s, a_d, as_o, ad_o, F1, IN_F, bx, by, As, Bs, t);
        return;
    }
    int e = (blk - G1_BLKS) * 256 + t;
    if (e >= EP) return;
    int s, d;
    if (e < NE) { s = ei[e]; d = ei[NE + e]; } else { s = d = e - NE; }
    int pos = atomicAdd(&cursor[d], 1);
    csr_src[pos] = s;
    csr_dst[pos] = d;
}

__global__ __launch_bounds__(256) void k_gemm2(const unsigned short* __restrict__ A,
                                               const unsigned short* __restrict__ B,
                                               unsigned short* __restrict__ C,
                                               const float* __restrict__ a_s,
                                               const float* __restrict__ a_d,
                                               float* __restrict__ as_o,
                                               float* __restrict__ ad_o) {
    __shared__ __align__(16) unsigned short As[8192];
    __shared__ __align__(16) unsigned short Bs[8192];
    int blk = blockIdx.x, t = threadIdx.x;
    int by = (blk & 7) + 8 * (blk >> 4);
    int bx = (blk >> 3) & 1;
    if (by < 125)
        gemm_body<32, 7, 2>(A, B, C, a_s, a_d, as_o, ad_o, F2, F1, bx, by, As, Bs, t);
}

// ---------------- edge q-values: layer-1 exp in bf16 (for gat1 A-build) ----------
__global__ __launch_bounds__(256) void k_el1(const int* __restrict__ csr_src,
                                             const int* __restrict__ csr_dst,
                                             const float* __restrict__ as1,
                                             const float* __restrict__ ad1,
                                             unsigned short* __restrict__ el16) {
    int j = blockIdx.x * 256 + threadIdx.x;
    if (j >= EP) return;
    int s = csr_src[j], d = csr_dst[j];
    float4 av = *(const float4*)&as1[s * H1C];
    float4 dv = *(const float4*)&ad1[d * H1C];
    us4 o;
    o[0] = rne_bf16(expf(lrelu02(av.x + dv.x)));
    o[1] = rne_bf16(expf(lrelu02(av.y + dv.y)));
    o[2] = rne_bf16(expf(lrelu02(av.z + dv.z)));
    o[3] = rne_bf16(expf(lrelu02(av.w + dv.w)));
    *(us4*)&el16[(size_t)j * 4] = o;
}

__global__ __launch_bounds__(256) void k_el2(const int* __restrict__ csr_src,
                                             const int* __restrict__ csr_dst,
                                             const float* __restrict__ as2,
                                             const float* __restrict__ ad2,
                                             float* __restrict__ el) {
    int j = blockIdx.x * 256 + threadIdx.x;
    if (j >= EP) return;
    int s = csr_src[j], d = csr_dst[j];
    float2 av = *(const float2*)&as2[s * 2];
    float2 dv = *(const float2*)&ad2[d * 2];
    float2 o;
    o.x = expf(lrelu02(av.x + dv.x));
    o.y = expf(lrelu02(av.y + dv.y));
    *(float2*)&el[(size_t)j * 2] = o;
}

// ---------------- layer-1: r6 version (verified passing @~85us) ------
// MFMA SpMM gather, XCD-sliced, double-buffered, DPP/perm 16b transpose, skewed
// banks, A-frag masked alphas, denom-via-ones-MFMA.
#define ISSUE1(CH, BUF, DV, EV)                                                   \
    {   int slot_ = beg + (CH) * 32 + lA;                                         \
        int sc_ = slot_ < end ? slot_ : end - 1;                                  \
        DV = (slot_ < end) ? csrd[sc_] : -1;                                      \
        EV = (int)el16[(size_t)sc_ * 4 + h];                                      \
        _Pragma("unroll")                                                         \
        for (int cc = 0; cc < 8; ++cc) {                                          \
            int slot2_ = beg + (CH) * 32 + cc * 4 + slot_in;                      \
            int sc3_ = slot2_ < end ? slot2_ : end - 1;                           \
            GLDS16(hb + (size_t)csr[sc3_] * F1 + gfeat,                           \
                   (BUF) + cc * 1024 + (cc >> 1) * 64);                           \
        } }

#define STEP1(CH, BUF, DV, EV)                                                    \
    {   if ((CH) + 1 < nch) asm volatile("s_waitcnt vmcnt(16)" ::: "memory");     \
        else                asm volatile("s_waitcnt vmcnt(0)" ::: "memory");      \
        us8 au;                                                                   \
        _Pragma("unroll")                                                         \
        for (int j = 0; j < 8; ++j) {                                             \
            int dvj = __shfl(DV, g * 8 + j);                                      \
            int evj = __shfl(EV, g * 8 + j);                                      \
            au[j] = (dvj == d0 + c) ? (unsigned short)evj : (unsigned short)0;    \
        }                                                                         \
        bf16x8 af = *(bf16x8*)&au;                                                \
        const char* rbc_ = (BUF) + g * 2112 + u * 4 + (odd ? 0 : 32);             \
        uint4 qq[8];                                                              \
        _Pragma("unroll")                                                         \
        for (int fb = 0; fb < 8; ++fb) {                                          \
            const unsigned* p = (const unsigned*)(rbc_ + fb * 128);               \
            unsigned W0 = p[0], W1 = p[16], W2 = p[256], W3 = p[272];             \
            unsigned X0 = (unsigned)__builtin_amdgcn_mov_dpp((int)W0, 0xB1, 0xF, 0xF, true); \
            unsigned X1 = (unsigned)__builtin_amdgcn_mov_dpp((int)W1, 0xB1, 0xF, 0xF, true); \
            unsigned X2 = (unsigned)__builtin_amdgcn_mov_dpp((int)W2, 0xB1, 0xF, 0xF, true); \
            unsigned X3 = (unsigned)__builtin_amdgcn_mov_dpp((int)W3, 0xB1, 0xF, 0xF, true); \
            qq[fb].x = __builtin_amdgcn_perm(W0, X0, sel);                        \
            qq[fb].y = __builtin_amdgcn_perm(W1, X1, sel);                        \
            qq[fb].z = __builtin_amdgcn_perm(W2, X2, sel);                        \
            qq[fb].w = __builtin_amdgcn_perm(W3, X3, sel);                        \
        }                                                                         \
        asm volatile("s_waitcnt lgkmcnt(0)" ::: "memory");                        \
        __builtin_amdgcn_sched_barrier(0);                                       \
        if ((CH) + 2 < nch) ISSUE1((CH) + 2, BUF, DV, EV);                        \
        dacc = __builtin_amdgcn_mfma_f32_16x16x32_bf16(af, ones, dacc, 0, 0, 0);  \
        _Pragma("unroll")                                                         \
        for (int fb = 0; fb < 8; ++fb) {                                          \
            bf16x8 bfv = *(bf16x8*)&qq[fb];                                       \
            acc[fb] = __builtin_amdgcn_mfma_f32_16x16x32_bf16(af, bfv, acc[fb], 0, 0, 0); \
        } }

__global__ __launch_bounds__(128) void k_gat1(const unsigned short* __restrict__ hb,
                                              const unsigned short* __restrict__ el16,
                                              const int* __restrict__ off,
                                              const int* __restrict__ csr,
                                              const int* __restrict__ csrd,
                                              const float* __restrict__ b1,
                                              unsigned short* __restrict__ h1b) {
    __shared__ __align__(16) char sbuf[2][2][8384];   // [wave][parity]
    const int t = threadIdx.x, l = t & 63, w = t >> 6;
    const int s = blockIdx.x & 7;               // feature slice == XCD
    const int db = (blockIdx.x >> 3) * 2 + w;   // dst block (0..999)
    const int d0 = db * 16;
    const int h = s >> 1;                       // head of this slice
    const int g = l >> 4, c = l & 15;
    const int u = c >> 1, odd = c & 1;          // feat-pair index / parity
    const int beg = off[d0], end = off[d0 + 16];
    char* buf0 = sbuf[w][0];
    char* buf1 = sbuf[w][1];
    const unsigned sel = odd ? 0x03020706u : 0x05040100u;
    const int gfeat = s * 128 + (l >> 3) * 16 + (l & 1) * 8;  // elem offset in row
    const int slot_in = (l >> 1) & 3;                          // slot within GLDS call
    const int lA = l & 31;                                     // A-slot lane

    f32x4 acc[8] = {};
    f32x4 dacc = {};
    us8 onesu = {0x3F80, 0x3F80, 0x3F80, 0x3F80, 0x3F80, 0x3F80, 0x3F80, 0x3F80};
    bf16x8 ones = *(bf16x8*)&onesu;

    const int nch = (end - beg + 31) >> 5;
    int dv0, ev0, dv1 = -1, ev1 = 0;
    ISSUE1(0, buf0, dv0, ev0);
    asm volatile("" ::: "memory");              // chunk0 ops before chunk1 ops
    if (nch > 1) ISSUE1(1, buf1, dv1, ev1);
    for (int ch = 0; ch < nch; ch += 2) {
        STEP1(ch, buf0, dv0, ev0);
        if (ch + 1 < nch) STEP1(ch + 1, buf1, dv1, ev1);
    }
    // epilogue: D row = d0 + g*4 + i (dst), col = feat fb*16 + c; denom from dacc
    float rdh[4];
#pragma unroll
    for (int i = 0; i < 4; ++i) rdh[i] = 1.f / (dacc[i] + 1e-16f);
#pragma unroll
    for (int fb = 0; fb < 8; ++fb) {
        int f = s * 128 + fb * 16 + c;
        float bias = b1[f];
#pragma unroll
        for (int i = 0; i < 4; ++i) {
            int r = d0 + g * 4 + i;
            float v = eluf(acc[fb][i] * rdh[i] + bias);
            h1b[(size_t)r * F1 + f] = rne_bf16(v);
        }
    }
}

// ---------------- layer-2: wave-per-node, q-softmax, packed-FMA, head-mean ----------------
__global__ __launch_bounds__(256) void k_gat2(const unsigned short* __restrict__ h2b,
                                              const float* __restrict__ el,
                                              const int* __restrict__ off,
                                              const int* __restrict__ csr,
                                              const float* __restrict__ b2,
                                              float* __restrict__ out_h2) {
    const int l = threadIdx.x & 63;
    const int d = blockIdx.x * 4 + (threadIdx.x >> 6);
    const int beg = off[d], end = off[d + 1];
    const int c = l & 31, p = l >> 5;
    const int myhead = c >> 4;
    const int hw = p;

    float s0 = 0.f, s1 = 0.f;
    for (int j = beg + l; j < end; j += 64) {
        float2 e = *(const float2*)&el[(size_t)j * 2];
        s0 += e.x; s1 += e.y;
    }
    for (int o = 32; o > 0; o >>= 1) {
        s0 += __shfl_down(s0, o);
        s1 += __shfl_down(s1, o);
    }
    s0 = __shfl(s0, 0); s1 = __shfl(s1, 0);
    float rdhw = 1.f / ((hw ? s1 : s0) + 1e-16f);

    f32x2 acc[4] = {};
    const unsigned int* base = (const unsigned int*)h2b + c * 4;
    for (int cbeg = beg; cbeg < end; cbeg += 32) {
        int cnt = end - cbeg; if (cnt > 32) cnt = 32;
        int idx = cbeg + c;
        int idxc = idx < end ? idx : end - 1;
        int s_sel = csr[idxc];
        float ev = el[(size_t)idxc * 2 + hw];
        float myw = (idx < end) ? ev * rdhw : 0.f;
        for (int jj = 0; jj < cnt; jj += 8) {
            int e0 = jj + p * 4;
            int sa = __shfl(s_sel, e0 + 0);
            int sb = __shfl(s_sel, e0 + 1);
            int sc = __shfl(s_sel, e0 + 2);
            int sd = __shfl(s_sel, e0 + 3);
            float wa = __shfl(myw, (myhead << 5) | (e0 + 0));
            float wb = __shfl(myw, (myhead << 5) | (e0 + 1));
            float wc = __shfl(myw, (myhead << 5) | (e0 + 2));
            float wd = __shfl(myw, (myhead << 5) | (e0 + 3));
            uint4 va = *(const uint4*)(base + (unsigned)sa * (F2 / 2));
            uint4 vb = *(const uint4*)(base + (unsigned)sb * (F2 / 2));
            uint4 vc = *(const uint4*)(base + (unsigned)sc * (F2 / 2));
            uint4 vd = *(const uint4*)(base + (unsigned)sd * (F2 / 2));
            f32x2 wa2 = {wa, wa}, wb2 = {wb, wb}, wc2 = {wc, wc}, wd2 = {wd, wd};
            acc[0] += wa2 * cvt2(va.x); acc[1] += wa2 * cvt2(va.y);
            acc[2] += wa2 * cvt2(va.z); acc[3] += wa2 * cvt2(va.w);
            acc[0] += wb2 * cvt2(vb.x); acc[1] += wb2 * cvt2(vb.y);
            acc[2] += wb2 * cvt2(vb.z); acc[3] += wb2 * cvt2(vb.w);
            acc[0] += wc2 * cvt2(vc.x); acc[1] += wc2 * cvt2(vc.y);
            acc[2] += wc2 * cvt2(vc.z); acc[3] += wc2 * cvt2(vc.w);
            acc[0] += wd2 * cvt2(vd.x); acc[1] += wd2 * cvt2(vd.y);
            acc[2] += wd2 * cvt2(vd.z); acc[3] += wd2 * cvt2(vd.w);
        }
    }
    float af[8] = {acc[0].x, acc[0].y, acc[1].x, acc[1].y,
                   acc[2].x, acc[2].y, acc[3].x, acc[3].y};
#pragma unroll
    for (int i = 0; i < 8; ++i) af[i] += __shfl(af[i], l ^ 32);
    float pt[8];
#pragma unroll
    for (int i = 0; i < 8; ++i) pt[i] = __shfl(af[i], l ^ 16);
    if (l < 16) {
        int f = l * 8;
        float o[8];
#pragma unroll
        for (int i = 0; i < 8; ++i) o[i] = eluf(0.5f * (af[i] + pt[i]) + b2[f + i]);
        *(float4*)&out_h2[(size_t)d * OUTF + f]     = make_float4(o[0], o[1], o[2], o[3]);
        *(float4*)&out_h2[(size_t)d * OUTF + f + 4] = make_float4(o[4], o[5], o[6], o[7]);
    }
}

// ---------------- pool (sorted batch) + projection + LayerNorm ----------------
__global__ __launch_bounds__(1024) void k_proj_ln(const float* __restrict__ h2,
                                                  const int* __restrict__ batch,
                                                  const float* __restrict__ pW,
                                                  const float* __restrict__ pb,
                                                  const float* __restrict__ g,
                                                  const float* __restrict__ be,
                                                  float* __restrict__ out) {
    __shared__ float part[1024];
    __shared__ float ph[OUTF];
    __shared__ float zb[768];
    __shared__ float red[1024];
    __shared__ float s_mu, s_rstd;
    int b = blockIdx.x, t = threadIdx.x;
    int lo = 0, hi = NN;
    while (lo < hi) { int mid = (lo + hi) >> 1; if (batch[mid] < b) lo = mid + 1; else hi = mid; }
    int n0 = lo;
    lo = 0; hi = NN;
    while (lo < hi) { int mid = (lo + hi) >> 1; if (batch[mid] < b + 1) lo = mid + 1; else hi = mid; }
    int n1 = lo;
    {
        int f = t & 127, slot = t >> 7;
        float a = 0.f;
        for (int n = n0 + slot; n < n1; n += 8) a += h2[(size_t)n * OUTF + f];
        part[t] = a;
    }
    __syncthreads();
    if (t < OUTF) {
        float s = 0.f;
#pragma unroll
        for (int k = 0; k < 8; ++k) s += part[k * 128 + t];
        float c = (float)(n1 - n0);
        c = c < 1.f ? 1.f : c;
        ph[t] = s / c;
    }
    __syncthreads();
    if (t < 768) {
        float acc = pb[t];
        for (int k = 0; k < OUTF; k += 4) {
            float4 w = *(const float4*)&pW[(size_t)t * OUTF + k];
            acc += w.x * ph[k] + w.y * ph[k + 1] + w.z * ph[k + 2] + w.w * ph[k + 3];
        }
        zb[t] = acc;
    }
    __syncthreads();
    red[t] = (t < 768) ? zb[t] : 0.f;
    __syncthreads();
    for (int ofs = 512; ofs > 0; ofs >>= 1) {
        if (t < ofs) red[t] += red[t + ofs];
        __syncthreads();
    }
    if (t == 0) s_mu = red[0] / 768.f;
    __syncthreads();
    float mu = s_mu;
    float dv = (t < 768) ? (zb[t] - mu) : 0.f;
    red[t] = dv * dv;
    __syncthreads();
    for (int ofs = 512; ofs > 0; ofs >>= 1) {
        if (t < ofs) red[t] += red[t + ofs];
        __syncthreads();
    }
    if (t == 0) s_rstd = rsqrtf(red[0] / 768.f + 1e-5f);
    __syncthreads();
    float rstd = s_rstd;
    if (t < 768)
        out[(size_t)b * 768 + t] = (zb[t] - mu) * rstd * g[t] + be[t];
}

extern "C" void kernel_launch(void* const* d_in, const int* in_sizes, int n_in,
                              void* d_out, int out_size, void* d_ws, size_t ws_size,
                              hipStream_t stream) {
    const float* x    = (const float*)d_in[0];
    const int*   ei   = (const int*)d_in[1];
    const int*   batch= (const int*)d_in[2];
    const float* W1   = (const float*)d_in[3];
    const float* a1s  = (const float*)d_in[4];
    const float* a1d  = (const float*)d_in[5];
    const float* b1   = (const float*)d_in[6];
    const float* W2   = (const float*)d_in[7];
    const float* a2s  = (const float*)d_in[8];
    const float* a2d  = (const float*)d_in[9];
    const float* b2   = (const float*)d_in[10];
    const float* pW   = (const float*)d_in[11];
    const float* pb   = (const float*)d_in[12];
    const float* lng  = (const float*)d_in[13];
    const float* lnb  = (const float*)d_in[14];

    float* out_ge = (float*)d_out;                 // (32, 768)
    float* out_h2 = (float*)d_out + BG * 768;      // (16000, 128)

    char* w = (char*)d_ws;
    unsigned short* xb   = (unsigned short*)w;  w += (size_t)NN * IN_F * 2;
    unsigned short* W1b  = (unsigned short*)w;  w += (size_t)F1 * IN_F * 2;
    unsigned short* W2b  = (unsigned short*)w;  w += (size_t)F2 * F1 * 2;
    unsigned short* hbufb= (unsigned short*)w;  w += (size_t)NN * F1 * 2;
    unsigned short* h1b  = (unsigned short*)w;  w += (size_t)NN * F1 * 2;
    unsigned short* h2b  = (unsigned short*)w;  w += (size_t)NN * F2 * 2;
    // zeroed region: as1, ad1, as2, ad2, deg (contiguous, one memset)
    float* as1  = (float*)w;  w += (size_t)NN * H1C * 4;
    float* ad1  = (float*)w;  w += (size_t)NN * H1C * 4;
    float* as2  = (float*)w;  w += (size_t)NN * H2C * 4;
    float* ad2  = (float*)w;  w += (size_t)NN * H2C * 4;
    int* deg    = (int*)w;    w += (size_t)NN * 4;
    int* off    = (int*)w;    w += (size_t)(NN + 4) * 4;
    int* cursor = (int*)w;    w += (size_t)NN * 4;
    int* csr    = (int*)w;    w += (size_t)EP * 4;
    int* csrd   = (int*)w;    w += (size_t)EP * 4;
    unsigned short* el16 = (unsigned short*)w;  w += (size_t)EP * H1C * 2;
    float* el2  = (float*)w;  w += (size_t)EP * H2C * 4;

    hipMemsetAsync(as1, 0, (size_t)NN * (H1C + H1C + H2C + H2C + 1) * 4, stream);

    k_prep<<<NB_PREP, 256, 0, stream>>>(x, W1, W2, xb, W1b, W2b, ei, deg);
    k_scan<<<1, 1024, 0, stream>>>(deg, off, cursor);

    k_gemm1<<<G1_BLKS + NB_H, 256, 0, stream>>>(xb, W1b, hbufb, a1s, a1d, as1, ad1,
                                                ei, cursor, csr, csrd);
    k_el1<<<(EP + 255) / 256, 256, 0, stream>>>(csr, csrd, as1, ad1, el16);
    k_gat1<<<4000, 128, 0, stream>>>(hbufb, el16, off, csr, csrd, b1, h1b);

    k_gemm2<<<256, 256, 0, stream>>>(h1b, W2b, h2b, a2s, a2d, as2, ad2);
    k_el2<<<(EP + 255) / 256, 256, 0, stream>>>(csr, csrd, as2, ad2, el2);
    k_gat2<<<NN / 4, 256, 0, stream>>>(h2b, el2, off, csr, b2, out_h2);

    k_proj_ln<<<BG, 1024, 0, stream>>>(out_h2, batch, pW, pb, lng, lnb, out_ge);
}

// Round 11
// 406.437 us; speedup vs baseline: 1.0164x; 1.0164x over previous
//
#include <hip/hip_runtime.h>
#include <cstddef>

#define NN   16000          // nodes
#define NE   256000         // edges (without self loops)
#define EP   (NE + NN)      // 272000 with self loops
#define BG   32             // graphs
#define IN_F 768
#define HID  256
#define H1C  4
#define F1   (H1C * HID)    // 1024
#define OUTF 128
#define H2C  2
#define F2   (H2C * OUTF)   // 256

typedef __bf16 bf16x8 __attribute__((ext_vector_type(8)));
typedef float  f32x4  __attribute__((ext_vector_type(4)));
typedef float  f32x2  __attribute__((ext_vector_type(2)));
typedef unsigned short us8 __attribute__((ext_vector_type(8)));
typedef unsigned short us4 __attribute__((ext_vector_type(4)));

static __device__ __forceinline__ float lrelu02(float x) { return x > 0.f ? x : 0.2f * x; }
static __device__ __forceinline__ float eluf(float x)    { return x > 0.f ? x : expm1f(x); }
static __device__ __forceinline__ unsigned short rne_bf16(float f) {
    unsigned u = __float_as_uint(f);
    return (unsigned short)((u + 0x7fffu + ((u >> 16) & 1u)) >> 16);
}
static __device__ __forceinline__ f32x2 cvt2(unsigned int u) {
    f32x2 r;
    r.x = __uint_as_float(u << 16);
    r.y = __uint_as_float(u & 0xffff0000u);
    return r;
}

#define GLDS16(gp, lp) __builtin_amdgcn_global_load_lds(                         \
    (const __attribute__((address_space(1))) void*)(gp),                          \
    (__attribute__((address_space(3))) void*)(lp), 16, 0, 0)

// ---------------- prep mega-kernel: 3x f2b + hist ----------------
#define NB_X  ((NN * IN_F) / 1024)      // 12000
#define NB_W1 ((F1 * IN_F) / 1024)      // 768
#define NB_W2 ((F2 * F1) / 1024)        // 256
#define NB_H  ((EP + 255) / 256)        // 1063
#define NB_PREP (NB_X + NB_W1 + NB_W2 + NB_H)

static __device__ __forceinline__ void f2b_body(const float* __restrict__ in,
                                                unsigned short* __restrict__ out,
                                                int blk, int t) {
    int i = (blk * 256 + t) * 4;
    float4 v = *(const float4*)&in[i];
    ushort4 o;
    o.x = rne_bf16(v.x); o.y = rne_bf16(v.y); o.z = rne_bf16(v.z); o.w = rne_bf16(v.w);
    *(ushort4*)&out[i] = o;
}

__global__ __launch_bounds__(256) void k_prep(const float* __restrict__ x,
                                              const float* __restrict__ W1,
                                              const float* __restrict__ W2,
                                              unsigned short* __restrict__ xb,
                                              unsigned short* __restrict__ W1b,
                                              unsigned short* __restrict__ W2b,
                                              const int* __restrict__ ei,
                                              int* __restrict__ deg) {
    int b = blockIdx.x, t = threadIdx.x;
    if (b < NB_X) { f2b_body(x, xb, b, t); return; }
    b -= NB_X;
    if (b < NB_W1) { f2b_body(W1, W1b, b, t); return; }
    b -= NB_W1;
    if (b < NB_W2) { f2b_body(W2, W2b, b, t); return; }
    b -= NB_W2;
    int e = b * 256 + t;
    if (e >= EP) return;
    int d = (e < NE) ? ei[NE + e] : (e - NE);
    atomicAdd(&deg[d], 1);
}

__global__ __launch_bounds__(1024) void k_scan(const int* __restrict__ deg,
                                               int* __restrict__ off, int* __restrict__ cursor) {
    __shared__ int sums[1024];
    int t = threadIdx.x;
    const int CH = 16;
    int base = t * CH;
    int s = 0;
    for (int i = 0; i < CH; ++i) { int idx = base + i; if (idx < NN) s += deg[idx]; }
    sums[t] = s;
    __syncthreads();
    for (int ofs = 1; ofs < 1024; ofs <<= 1) {
        int v = 0;
        if (t >= ofs) v = sums[t - ofs];
        __syncthreads();
        sums[t] += v;
        __syncthreads();
    }
    int run = sums[t] - s;
    for (int i = 0; i < CH; ++i) {
        int idx = base + i;
        if (idx < NN) { off[idx] = run; cursor[idx] = run; run += deg[idx]; }
    }
    if (t == 1023) off[NN] = run;
}

// ------- BM=128 BN=128 BK=32 bf16 MFMA GEMM body, counted-vmcnt pipeline ---------
// r11: r10's __syncthreads() drained vmcnt(0) before every s_barrier (compiler
// semantics) -> the "2-phase" never pipelined; ~900cy HBM latency exposed per
// K-step (the measured 88us/MfmaUtil 11%). Now: raw s_barrier + counted vmcnt(4),
// wait at TOP of each phase -> each stage gets a FULL K-step of slack and loads
// stay in flight across barriers (T3+T4 minimum template). Hazards audited:
// barrier-after-wait publishes tile cross-wave; barrier-after-MFMA protects the
// buffer before re-stage (ds_read->MFMA deps imply reads complete); per-iter
// VMEM = exactly 4 GLDS so counts are exact; KITER even; tail takes vmcnt(0).
// Bank-swizzle (r10, conflicts 3.07M->0) retained.
#define GEMM_MM16(POFS)                                                              \
    {   bf16x8 a0 = pa[(POFS)], a1 = pa[(POFS) + 64], a2 = pa[(POFS) + 128],         \
               a3 = pa[(POFS) + 192];                                                \
        bf16x8 b0 = pb[(POFS)], b1 = pb[(POFS) + 64], b2 = pb[(POFS) + 128],         \
               b3 = pb[(POFS) + 192];                                                \
        acc[0][0] = __builtin_amdgcn_mfma_f32_16x16x32_bf16(a0, b0, acc[0][0], 0, 0, 0); \
        acc[0][1] = __builtin_amdgcn_mfma_f32_16x16x32_bf16(a0, b1, acc[0][1], 0, 0, 0); \
        acc[0][2] = __builtin_amdgcn_mfma_f32_16x16x32_bf16(a0, b2, acc[0][2], 0, 0, 0); \
        acc[0][3] = __builtin_amdgcn_mfma_f32_16x16x32_bf16(a0, b3, acc[0][3], 0, 0, 0); \
        acc[1][0] = __builtin_amdgcn_mfma_f32_16x16x32_bf16(a1, b0, acc[1][0], 0, 0, 0); \
        acc[1][1] = __builtin_amdgcn_mfma_f32_16x16x32_bf16(a1, b1, acc[1][1], 0, 0, 0); \
        acc[1][2] = __builtin_amdgcn_mfma_f32_16x16x32_bf16(a1, b2, acc[1][2], 0, 0, 0); \
        acc[1][3] = __builtin_amdgcn_mfma_f32_16x16x32_bf16(a1, b3, acc[1][3], 0, 0, 0); \
        acc[2][0] = __builtin_amdgcn_mfma_f32_16x16x32_bf16(a2, b0, acc[2][0], 0, 0, 0); \
        acc[2][1] = __builtin_amdgcn_mfma_f32_16x16x32_bf16(a2, b1, acc[2][1], 0, 0, 0); \
        acc[2][2] = __builtin_amdgcn_mfma_f32_16x16x32_bf16(a2, b2, acc[2][2], 0, 0, 0); \
        acc[2][3] = __builtin_amdgcn_mfma_f32_16x16x32_bf16(a2, b3, acc[2][3], 0, 0, 0); \
        acc[3][0] = __builtin_amdgcn_mfma_f32_16x16x32_bf16(a3, b0, acc[3][0], 0, 0, 0); \
        acc[3][1] = __builtin_amdgcn_mfma_f32_16x16x32_bf16(a3, b1, acc[3][1], 0, 0, 0); \
        acc[3][2] = __builtin_amdgcn_mfma_f32_16x16x32_bf16(a3, b2, acc[3][2], 0, 0, 0); \
        acc[3][3] = __builtin_amdgcn_mfma_f32_16x16x32_bf16(a3, b3, acc[3][3], 0, 0, 0); }

#define GEMM_STAGE(IT, OFS)                                                          \
    {   const unsigned short* pA_ = ga0 + (IT) * 32;                                 \
        const unsigned short* pB_ = gb0 + (IT) * 32;                                 \
        GLDS16(pA_, lA0 + (OFS)); GLDS16(pA_ + K64, lA1 + (OFS));                    \
        GLDS16(pB_, lB0 + (OFS)); GLDS16(pB_ + K64, lB1 + (OFS)); }

template <int KITER, int HSHIFT, int HCNT>
static __device__ __forceinline__ void gemm_body(const unsigned short* __restrict__ A,
                                                 const unsigned short* __restrict__ B,
                                                 unsigned short* __restrict__ C,
                                                 const float* __restrict__ a_s,
                                                 const float* __restrict__ a_d,
                                                 float* __restrict__ as_o,
                                                 float* __restrict__ ad_o,
                                                 int N, int K, int bx, int by,
                                                 unsigned short* As, unsigned short* Bs,
                                                 int t) {
    const int w = t >> 6, lane = t & 63;
    const int m0 = by * 128, n0 = bx * 128;
    const int wm = (w >> 1) * 64, wn = (w & 1) * 64;

    const int qsw = (t & 3) ^ ((t >> 3) & 3);        // pre-swizzled source quarter
    const unsigned short* ga0 = A + (size_t)(m0 + (t >> 2)) * K + qsw * 8;
    const unsigned short* gb0 = B + (size_t)(n0 + (t >> 2)) * K + qsw * 8;
    const size_t K64 = (size_t)64 * K;

    unsigned short* lA0 = &As[w * 512];              // buf0, rows 0..63 (wave quarter)
    unsigned short* lA1 = &As[w * 512 + 2048];       // buf0, rows 64..127
    unsigned short* lB0 = &Bs[w * 512];
    unsigned short* lB1 = &Bs[w * 512 + 2048];

    f32x4 acc[4][4] = {};

    const int slot = (lane >> 4) ^ ((lane >> 1) & 3);   // swizzled read slot
    const bf16x8* pa = (const bf16x8*)As + (wm + (lane & 15)) * 4 + slot;
    const bf16x8* pb = (const bf16x8*)Bs + (wn + (lane & 15)) * 4 + slot;

    GEMM_STAGE(0, 0);                                // prologue: 2 K-steps in flight
    GEMM_STAGE(1, 4096);
    for (int it = 0; it < KITER; it += 2) {
        // ---- phase A: compute buf0 (K-step it) ----
        if (it + 1 < KITER) asm volatile("s_waitcnt vmcnt(4)" ::: "memory");
        else                asm volatile("s_waitcnt vmcnt(0)" ::: "memory");
        __builtin_amdgcn_s_barrier();                // tile(it) published to all waves
        GEMM_MM16(0);
        __builtin_amdgcn_s_barrier();                // all waves done reading buf0
        if (it + 2 < KITER) GEMM_STAGE(it + 2, 0);
        // ---- phase B: compute buf1 (K-step it+1) ----
        if (it + 2 < KITER) asm volatile("s_waitcnt vmcnt(4)" ::: "memory");
        else                asm volatile("s_waitcnt vmcnt(0)" ::: "memory");
        __builtin_amdgcn_s_barrier();
        GEMM_MM16(512);
        __builtin_amdgcn_s_barrier();
        if (it + 3 < KITER) GEMM_STAGE(it + 3, 4096);
    }
    const int ccol = n0 + wn + (lane & 15);
    const int crow = m0 + wm + (lane >> 4) * 4;
#pragma unroll
    for (int mi = 0; mi < 4; ++mi)
#pragma unroll
        for (int i = 0; i < 4; ++i) {
            unsigned short* cp = C + (size_t)(crow + mi * 16 + i) * N + ccol;
            cp[0]  = rne_bf16(acc[mi][0][i]);
            cp[16] = rne_bf16(acc[mi][1][i]);
            cp[32] = rne_bf16(acc[mi][2][i]);
            cp[48] = rne_bf16(acc[mi][3][i]);
        }
    const int hh = n0 >> HSHIFT;
    float asv[4], adv[4];
#pragma unroll
    for (int bi = 0; bi < 4; ++bi) {
        asv[bi] = a_s[ccol + bi * 16];
        adv[bi] = a_d[ccol + bi * 16];
    }
#pragma unroll
    for (int mi = 0; mi < 4; ++mi)
#pragma unroll
        for (int i = 0; i < 4; ++i) {
            float vs = acc[mi][0][i] * asv[0] + acc[mi][1][i] * asv[1]
                     + acc[mi][2][i] * asv[2] + acc[mi][3][i] * asv[3];
            float vd = acc[mi][0][i] * adv[0] + acc[mi][1][i] * adv[1]
                     + acc[mi][2][i] * adv[2] + acc[mi][3][i] * adv[3];
#pragma unroll
            for (int m = 1; m <= 8; m <<= 1) {
                vs += __shfl_xor(vs, m);
                vd += __shfl_xor(vd, m);
            }
            if ((lane & 15) == 0) {
                int r = crow + mi * 16 + i;
                atomicAdd(&as_o[r * HCNT + hh], vs);
                atomicAdd(&ad_o[r * HCNT + hh], vd);
            }
        }
}

// GEMM1: 125 panels x 8 col-blocks (BM=128); panel -> one XCD (weights L2-fit);
// CSR scatter as sequential tail blocks.
#define G1_BLKS 1024
__global__ __launch_bounds__(256) void k_gemm1(const unsigned short* __restrict__ A,
                                               const unsigned short* __restrict__ B,
                                               unsigned short* __restrict__ C,
                                               const float* __restrict__ a_s,
                                               const float* __restrict__ a_d,
                                               float* __restrict__ as_o,
                                               float* __restrict__ ad_o,
                                               const int* __restrict__ ei,
                                               int* __restrict__ cursor,
                                               int* __restrict__ csr_src,
                                               int* __restrict__ csr_dst) {
    __shared__ __align__(16) unsigned short As[8192];   // 2 halves x 8KB (dbuf)
    __shared__ __align__(16) unsigned short Bs[8192];
    int blk = blockIdx.x, t = threadIdx.x;
    if (blk < G1_BLKS) {
        int by = (blk & 7) + 8 * (blk >> 6);
        int bx = (blk >> 3) & 7;
        if (by < 125)
            gemm_body<24, 8, 4>(A, B, C, a_s, a_d, as_o, ad_o, F1, IN_F, bx, by, As, Bs, t);
        return;
    }
    int e = (blk - G1_BLKS) * 256 + t;
    if (e >= EP) return;
    int s, d;
    if (e < NE) { s = ei[e]; d = ei[NE + e]; } else { s = d = e - NE; }
    int pos = atomicAdd(&cursor[d], 1);
    csr_src[pos] = s;
    csr_dst[pos] = d;
}

__global__ __launch_bounds__(256) void k_gemm2(const unsigned short* __restrict__ A,
                                               const unsigned short* __restrict__ B,
                                               unsigned short* __restrict__ C,
                                               const float* __restrict__ a_s,
                                               const float* __restrict__ a_d,
                                               float* __restrict__ as_o,
                                               float* __restrict__ ad_o) {
    __shared__ __align__(16) unsigned short As[8192];
    __shared__ __align__(16) unsigned short Bs[8192];
    int blk = blockIdx.x, t = threadIdx.x;
    int by = (blk & 7) + 8 * (blk >> 4);
    int bx = (blk >> 3) & 1;
    if (by < 125)
        gemm_body<32, 7, 2>(A, B, C, a_s, a_d, as_o, ad_o, F2, F1, bx, by, As, Bs, t);
}

// ---------------- edge q-values: layer-1 exp in bf16 (for gat1 A-build) ----------
__global__ __launch_bounds__(256) void k_el1(const int* __restrict__ csr_src,
                                             const int* __restrict__ csr_dst,
                                             const float* __restrict__ as1,
                                             const float* __restrict__ ad1,
                                             unsigned short* __restrict__ el16) {
    int j = blockIdx.x * 256 + threadIdx.x;
    if (j >= EP) return;
    int s = csr_src[j], d = csr_dst[j];
    float4 av = *(const float4*)&as1[s * H1C];
    float4 dv = *(const float4*)&ad1[d * H1C];
    us4 o;
    o[0] = rne_bf16(expf(lrelu02(av.x + dv.x)));
    o[1] = rne_bf16(expf(lrelu02(av.y + dv.y)));
    o[2] = rne_bf16(expf(lrelu02(av.z + dv.z)));
    o[3] = rne_bf16(expf(lrelu02(av.w + dv.w)));
    *(us4*)&el16[(size_t)j * 4] = o;
}

__global__ __launch_bounds__(256) void k_el2(const int* __restrict__ csr_src,
                                             const int* __restrict__ csr_dst,
                                             const float* __restrict__ as2,
                                             const float* __restrict__ ad2,
                                             float* __restrict__ el) {
    int j = blockIdx.x * 256 + threadIdx.x;
    if (j >= EP) return;
    int s = csr_src[j], d = csr_dst[j];
    float2 av = *(const float2*)&as2[s * 2];
    float2 dv = *(const float2*)&ad2[d * 2];
    float2 o;
    o.x = expf(lrelu02(av.x + dv.x));
    o.y = expf(lrelu02(av.y + dv.y));
    *(float2*)&el[(size_t)j * 2] = o;
}

// ---------------- layer-1: r6 version (verified passing @~85us) ------
// MFMA SpMM gather, XCD-sliced, double-buffered, DPP/perm 16b transpose, skewed
// banks, A-frag masked alphas, denom-via-ones-MFMA.
#define ISSUE1(CH, BUF, DV, EV)                                                   \
    {   int slot_ = beg + (CH) * 32 + lA;                                         \
        int sc_ = slot_ < end ? slot_ : end - 1;                                  \
        DV = (slot_ < end) ? csrd[sc_] : -1;                                      \
        EV = (int)el16[(size_t)sc_ * 4 + h];                                      \
        _Pragma("unroll")                                                         \
        for (int cc = 0; cc < 8; ++cc) {                                          \
            int slot2_ = beg + (CH) * 32 + cc * 4 + slot_in;                      \
            int sc3_ = slot2_ < end ? slot2_ : end - 1;                           \
            GLDS16(hb + (size_t)csr[sc3_] * F1 + gfeat,                           \
                   (BUF) + cc * 1024 + (cc >> 1) * 64);                           \
        } }

#define STEP1(CH, BUF, DV, EV)                                                    \
    {   if ((CH) + 1 < nch) asm volatile("s_waitcnt vmcnt(16)" ::: "memory");     \
        else                asm volatile("s_waitcnt vmcnt(0)" ::: "memory");      \
        us8 au;                                                                   \
        _Pragma("unroll")                                                         \
        for (int j = 0; j < 8; ++j) {                                             \
            int dvj = __shfl(DV, g * 8 + j);                                      \
            int evj = __shfl(EV, g * 8 + j);                                      \
            au[j] = (dvj == d0 + c) ? (unsigned short)evj : (unsigned short)0;    \
        }                                                                         \
        bf16x8 af = *(bf16x8*)&au;                                                \
        const char* rbc_ = (BUF) + g * 2112 + u * 4 + (odd ? 0 : 32);             \
        uint4 qq[8];                                                              \
        _Pragma("unroll")                                                         \
        for (int fb = 0; fb < 8; ++fb) {                                          \
            const unsigned* p = (const unsigned*)(rbc_ + fb * 128);               \
            unsigned W0 = p[0], W1 = p[16], W2 = p[256], W3 = p[272];             \
            unsigned X0 = (unsigned)__builtin_amdgcn_mov_dpp((int)W0, 0xB1, 0xF, 0xF, true); \
            unsigned X1 = (unsigned)__builtin_amdgcn_mov_dpp((int)W1, 0xB1, 0xF, 0xF, true); \
            unsigned X2 = (unsigned)__builtin_amdgcn_mov_dpp((int)W2, 0xB1, 0xF, 0xF, true); \
            unsigned X3 = (unsigned)__builtin_amdgcn_mov_dpp((int)W3, 0xB1, 0xF, 0xF, true); \
            qq[fb].x = __builtin_amdgcn_perm(W0, X0, sel);                        \
            qq[fb].y = __builtin_amdgcn_perm(W1, X1, sel);                        \
            qq[fb].z = __builtin_amdgcn_perm(W2, X2, sel);                        \
            qq[fb].w = __builtin_amdgcn_perm(W3, X3, sel);                        \
        }                                                                         \
        asm volatile("s_waitcnt lgkmcnt(0)" ::: "memory");                        \
        __builtin_amdgcn_sched_barrier(0);                                       \
        if ((CH) + 2 < nch) ISSUE1((CH) + 2, BUF, DV, EV);                        \
        dacc = __builtin_amdgcn_mfma_f32_16x16x32_bf16(af, ones, dacc, 0, 0, 0);  \
        _Pragma("unroll")                                                         \
        for (int fb = 0; fb < 8; ++fb) {                                          \
            bf16x8 bfv = *(bf16x8*)&qq[fb];                                       \
            acc[fb] = __builtin_amdgcn_mfma_f32_16x16x32_bf16(af, bfv, acc[fb], 0, 0, 0); \
        } }

__global__ __launch_bounds__(128) void k_gat1(const unsigned short* __restrict__ hb,
                                              const unsigned short* __restrict__ el16,
                                              const int* __restrict__ off,
                                              const int* __restrict__ csr,
                                              const int* __restrict__ csrd,
                                              const float* __restrict__ b1,
                                              unsigned short* __restrict__ h1b) {
    __shared__ __align__(16) char sbuf[2][2][8384];   // [wave][parity]
    const int t = threadIdx.x, l = t & 63, w = t >> 6;
    const int s = blockIdx.x & 7;               // feature slice == XCD
    const int db = (blockIdx.x >> 3) * 2 + w;   // dst block (0..999)
    const int d0 = db * 16;
    const int h = s >> 1;                       // head of this slice
    const int g = l >> 4, c = l & 15;
    const int u = c >> 1, odd = c & 1;          // feat-pair index / parity
    const int beg = off[d0], end = off[d0 + 16];
    char* buf0 = sbuf[w][0];
    char* buf1 = sbuf[w][1];
    const unsigned sel = odd ? 0x03020706u : 0x05040100u;
    const int gfeat = s * 128 + (l >> 3) * 16 + (l & 1) * 8;  // elem offset in row
    const int slot_in = (l >> 1) & 3;                          // slot within GLDS call
    const int lA = l & 31;                                     // A-slot lane

    f32x4 acc[8] = {};
    f32x4 dacc = {};
    us8 onesu = {0x3F80, 0x3F80, 0x3F80, 0x3F80, 0x3F80, 0x3F80, 0x3F80, 0x3F80};
    bf16x8 ones = *(bf16x8*)&onesu;

    const int nch = (end - beg + 31) >> 5;
    int dv0, ev0, dv1 = -1, ev1 = 0;
    ISSUE1(0, buf0, dv0, ev0);
    asm volatile("" ::: "memory");              // chunk0 ops before chunk1 ops
    if (nch > 1) ISSUE1(1, buf1, dv1, ev1);
    for (int ch = 0; ch < nch; ch += 2) {
        STEP1(ch, buf0, dv0, ev0);
        if (ch + 1 < nch) STEP1(ch + 1, buf1, dv1, ev1);
    }
    // epilogue: D row = d0 + g*4 + i (dst), col = feat fb*16 + c; denom from dacc
    float rdh[4];
#pragma unroll
    for (int i = 0; i < 4; ++i) rdh[i] = 1.f / (dacc[i] + 1e-16f);
#pragma unroll
    for (int fb = 0; fb < 8; ++fb) {
        int f = s * 128 + fb * 16 + c;
        float bias = b1[f];
#pragma unroll
        for (int i = 0; i < 4; ++i) {
            int r = d0 + g * 4 + i;
            float v = eluf(acc[fb][i] * rdh[i] + bias);
            h1b[(size_t)r * F1 + f] = rne_bf16(v);
        }
    }
}

// ---------------- layer-2: wave-per-node, q-softmax, packed-FMA, head-mean ----------------
__global__ __launch_bounds__(256) void k_gat2(const unsigned short* __restrict__ h2b,
                                              const float* __restrict__ el,
                                              const int* __restrict__ off,
                                              const int* __restrict__ csr,
                                              const float* __restrict__ b2,
                                              float* __restrict__ out_h2) {
    const int l = threadIdx.x & 63;
    const int d = blockIdx.x * 4 + (threadIdx.x >> 6);
    const int beg = off[d], end = off[d + 1];
    const int c = l & 31, p = l >> 5;
    const int myhead = c >> 4;
    const int hw = p;

    float s0 = 0.f, s1 = 0.f;
    for (int j = beg + l; j < end; j += 64) {
        float2 e = *(const float2*)&el[(size_t)j * 2];
        s0 += e.x; s1 += e.y;
    }
    for (int o = 32; o > 0; o >>= 1) {
        s0 += __shfl_down(s0, o);
        s1 += __shfl_down(s1, o);
    }
    s0 = __shfl(s0, 0); s1 = __shfl(s1, 0);
    float rdhw = 1.f / ((hw ? s1 : s0) + 1e-16f);

    f32x2 acc[4] = {};
    const unsigned int* base = (const unsigned int*)h2b + c * 4;
    for (int cbeg = beg; cbeg < end; cbeg += 32) {
        int cnt = end - cbeg; if (cnt > 32) cnt = 32;
        int idx = cbeg + c;
        int idxc = idx < end ? idx : end - 1;
        int s_sel = csr[idxc];
        float ev = el[(size_t)idxc * 2 + hw];
        float myw = (idx < end) ? ev * rdhw : 0.f;
        for (int jj = 0; jj < cnt; jj += 8) {
            int e0 = jj + p * 4;
            int sa = __shfl(s_sel, e0 + 0);
            int sb = __shfl(s_sel, e0 + 1);
            int sc = __shfl(s_sel, e0 + 2);
            int sd = __shfl(s_sel, e0 + 3);
            float wa = __shfl(myw, (myhead << 5) | (e0 + 0));
            float wb = __shfl(myw, (myhead << 5) | (e0 + 1));
            float wc = __shfl(myw, (myhead << 5) | (e0 + 2));
            float wd = __shfl(myw, (myhead << 5) | (e0 + 3));
            uint4 va = *(const uint4*)(base + (unsigned)sa * (F2 / 2));
            uint4 vb = *(const uint4*)(base + (unsigned)sb * (F2 / 2));
            uint4 vc = *(const uint4*)(base + (unsigned)sc * (F2 / 2));
            uint4 vd = *(const uint4*)(base + (unsigned)sd * (F2 / 2));
            f32x2 wa2 = {wa, wa}, wb2 = {wb, wb}, wc2 = {wc, wc}, wd2 = {wd, wd};
            acc[0] += wa2 * cvt2(va.x); acc[1] += wa2 * cvt2(va.y);
            acc[2] += wa2 * cvt2(va.z); acc[3] += wa2 * cvt2(va.w);
            acc[0] += wb2 * cvt2(vb.x); acc[1] += wb2 * cvt2(vb.y);
            acc[2] += wb2 * cvt2(vb.z); acc[3] += wb2 * cvt2(vb.w);
            acc[0] += wc2 * cvt2(vc.x); acc[1] += wc2 * cvt2(vc.y);
            acc[2] += wc2 * cvt2(vc.z); acc[3] += wc2 * cvt2(vc.w);
            acc[0] += wd2 * cvt2(vd.x); acc[1] += wd2 * cvt2(vd.y);
            acc[2] += wd2 * cvt2(vd.z); acc[3] += wd2 * cvt2(vd.w);
        }
    }
    float af[8] = {acc[0].x, acc[0].y, acc[1].x, acc[1].y,
                   acc[2].x, acc[2].y, acc[3].x, acc[3].y};
#pragma unroll
    for (int i = 0; i < 8; ++i) af[i] += __shfl(af[i], l ^ 32);
    float pt[8];
#pragma unroll
    for (int i = 0; i < 8; ++i) pt[i] = __shfl(af[i], l ^ 16);
    if (l < 16) {
        int f = l * 8;
        float o[8];
#pragma unroll
        for (int i = 0; i < 8; ++i) o[i] = eluf(0.5f * (af[i] + pt[i]) + b2[f + i]);
        *(float4*)&out_h2[(size_t)d * OUTF + f]     = make_float4(o[0], o[1], o[2], o[3]);
        *(float4*)&out_h2[(size_t)d * OUTF + f + 4] = make_float4(o[4], o[5], o[6], o[7]);
    }
}

// ---------------- pool (sorted batch) + projection + LayerNorm ----------------
__global__ __launch_bounds__(1024) void k_proj_ln(const float* __restrict__ h2,
                                                  const int* __restrict__ batch,
                                                  const float* __restrict__ pW,
                                                  const float* __restrict__ pb,
                                                  const float* __restrict__ g,
                                                  const float* __restrict__ be,
                                                  float* __restrict__ out) {
    __shared__ float part[1024];
    __shared__ float ph[OUTF];
    __shared__ float zb[768];
    __shared__ float red[1024];
    __shared__ float s_mu, s_rstd;
    int b = blockIdx.x, t = threadIdx.x;
    int lo = 0, hi = NN;
    while (lo < hi) { int mid = (lo + hi) >> 1; if (batch[mid] < b) lo = mid + 1; else hi = mid; }
    int n0 = lo;
    lo = 0; hi = NN;
    while (lo < hi) { int mid = (lo + hi) >> 1; if (batch[mid] < b + 1) lo = mid + 1; else hi = mid; }
    int n1 = lo;
    {
        int f = t & 127, slot = t >> 7;
        float a = 0.f;
        for (int n = n0 + slot; n < n1; n += 8) a += h2[(size_t)n * OUTF + f];
        part[t] = a;
    }
    __syncthreads();
    if (t < OUTF) {
        float s = 0.f;
#pragma unroll
        for (int k = 0; k < 8; ++k) s += part[k * 128 + t];
        float c = (float)(n1 - n0);
        c = c < 1.f ? 1.f : c;
        ph[t] = s / c;
    }
    __syncthreads();
    if (t < 768) {
        float acc = pb[t];
        for (int k = 0; k < OUTF; k += 4) {
            float4 w = *(const float4*)&pW[(size_t)t * OUTF + k];
            acc += w.x * ph[k] + w.y * ph[k + 1] + w.z * ph[k + 2] + w.w * ph[k + 3];
        }
        zb[t] = acc;
    }
    __syncthreads();
    red[t] = (t < 768) ? zb[t] : 0.f;
    __syncthreads();
    for (int ofs = 512; ofs > 0; ofs >>= 1) {
        if (t < ofs) red[t] += red[t + ofs];
        __syncthreads();
    }
    if (t == 0) s_mu = red[0] / 768.f;
    __syncthreads();
    float mu = s_mu;
    float dv = (t < 768) ? (zb[t] - mu) : 0.f;
    red[t] = dv * dv;
    __syncthreads();
    for (int ofs = 512; ofs > 0; ofs >>= 1) {
        if (t < ofs) red[t] += red[t + ofs];
        __syncthreads();
    }
    if (t == 0) s_rstd = rsqrtf(red[0] / 768.f + 1e-5f);
    __syncthreads();
    float rstd = s_rstd;
    if (t < 768)
        out[(size_t)b * 768 + t] = (zb[t] - mu) * rstd * g[t] + be[t];
}

extern "C" void kernel_launch(void* const* d_in, const int* in_sizes, int n_in,
                              void* d_out, int out_size, void* d_ws, size_t ws_size,
                              hipStream_t stream) {
    const float* x    = (const float*)d_in[0];
    const int*   ei   = (const int*)d_in[1];
    const int*   batch= (const int*)d_in[2];
    const float* W1   = (const float*)d_in[3];
    const float* a1s  = (const float*)d_in[4];
    const float* a1d  = (const float*)d_in[5];
    const float* b1   = (const float*)d_in[6];
    const float* W2   = (const float*)d_in[7];
    const float* a2s  = (const float*)d_in[8];
    const float* a2d  = (const float*)d_in[9];
    const float* b2   = (const float*)d_in[10];
    const float* pW   = (const float*)d_in[11];
    const float* pb   = (const float*)d_in[12];
    const float* lng  = (const float*)d_in[13];
    const float* lnb  = (const float*)d_in[14];

    float* out_ge = (float*)d_out;                 // (32, 768)
    float* out_h2 = (float*)d_out + BG * 768;      // (16000, 128)

    char* w = (char*)d_ws;
    unsigned short* xb   = (unsigned short*)w;  w += (size_t)NN * IN_F * 2;
    unsigned short* W1b  = (unsigned short*)w;  w += (size_t)F1 * IN_F * 2;
    unsigned short* W2b  = (unsigned short*)w;  w += (size_t)F2 * F1 * 2;
    unsigned short* hbufb= (unsigned short*)w;  w += (size_t)NN * F1 * 2;
    unsigned short* h1b  = (unsigned short*)w;  w += (size_t)NN * F1 * 2;
    unsigned short* h2b  = (unsigned short*)w;  w += (size_t)NN * F2 * 2;
    // zeroed region: as1, ad1, as2, ad2, deg (contiguous, one memset)
    float* as1  = (float*)w;  w += (size_t)NN * H1C * 4;
    float* ad1  = (float*)w;  w += (size_t)NN * H1C * 4;
    float* as2  = (float*)w;  w += (size_t)NN * H2C * 4;
    float* ad2  = (float*)w;  w += (size_t)NN * H2C * 4;
    int* deg    = (int*)w;    w += (size_t)NN * 4;
    int* off    = (int*)w;    w += (size_t)(NN + 4) * 4;
    int* cursor = (int*)w;    w += (size_t)NN * 4;
    int* csr    = (int*)w;    w += (size_t)EP * 4;
    int* csrd   = (int*)w;    w += (size_t)EP * 4;
    unsigned short* el16 = (unsigned short*)w;  w += (size_t)EP * H1C * 2;
    float* el2  = (float*)w;  w += (size_t)EP * H2C * 4;

    hipMemsetAsync(as1, 0, (size_t)NN * (H1C + H1C + H2C + H2C + 1) * 4, stream);

    k_prep<<<NB_PREP, 256, 0, stream>>>(x, W1, W2, xb, W1b, W2b, ei, deg);
    k_scan<<<1, 1024, 0, stream>>>(deg, off, cursor);

    k_gemm1<<<G1_BLKS + NB_H, 256, 0, stream>>>(xb, W1b, hbufb, a1s, a1d, as1, ad1,
                                                ei, cursor, csr, csrd);
    k_el1<<<(EP + 255) / 256, 256, 0, stream>>>(csr, csrd, as1, ad1, el16);
    k_gat1<<<4000, 128, 0, stream>>>(hbufb, el16, off, csr, csrd, b1, h1b);

    k_gemm2<<<256, 256, 0, stream>>>(h1b, W2b, h2b, a2s, a2d, as2, ad2);
    k_el2<<<(EP + 255) / 256, 256, 0, stream>>>(csr, csrd, as2, ad2, el2);
    k_gat2<<<NN / 4, 256, 0, stream>>>(h2b, el2, off, csr, b2, out_h2);

    k_proj_ln<<<BG, 1024, 0, stream>>>(out_h2, batch, pW, pb, lng, lnb, out_ge);
}